// Round 11
// baseline (257.863 us; speedup 1.0000x reference)
//
#include <hip/hip_runtime.h>
#include <cstddef>

#define N_NODES_C 50000
#define N_EDGES_C 800000

typedef _Float16 f16x8 __attribute__((ext_vector_type(8)));
typedef float    f32x4 __attribute__((ext_vector_type(4)));

constexpr int XSTR = 72;        // f16 stride for per-wave h buffer in mlp part
constexpr int MLP_BLOCKS  = 782;   // ceil(50000/64)
constexpr int DEG_BLOCKS  = 1563;  // ceil(800000/512), 2 edges/thread
constexpr int QC_BLOCKS   = 1564;  // 391 * 4 (flattened qcalc grid)

// ---------------------------------------------------------------------------
// prep (wT, W3T) + deg fused (deg: 2 edges/thread for ILP).
//  wT[l][j][k] = W_l[k][j] (f16)                      idx [0, 28672)
//  W3T[r=y*64+x][64 k] (f16), 16B chunks XOR-swizzled: chunk c of row r
//  stored at chunk c^(r&7). Value = w_out[k*2048 + r].   idx [28672, 159744)
// ---------------------------------------------------------------------------
__global__ void prep_deg_kernel(const float* __restrict__ w_in,
                                const float* __restrict__ w_mid,
                                const float* __restrict__ w_out,
                                const int* __restrict__ col,
                                _Float16* __restrict__ wT,
                                _Float16* __restrict__ W3T,
                                int* __restrict__ deg)
{
    const int b = blockIdx.x;
    if (b < 624) {
        const int idx = b * 256 + threadIdx.x;
        if (idx < 7 * 4096) {
            const int l = idx >> 12, rem = idx & 4095;
            const int j = rem >> 6, k = rem & 63;
            const float v = (l == 0) ? w_in[k * 64 + j]
                                     : w_mid[(size_t)(l - 1) * 4096 + k * 64 + j];
            wT[(size_t)l * 4096 + j * 64 + k] = (_Float16)v;
        } else {
            const int i2 = idx - 7 * 4096;   // < 131072
            const int r = i2 >> 6, k = i2 & 63;
            const int c = k >> 3;
            const int pos = ((c ^ (r & 7)) << 3) | (k & 7);
            W3T[(size_t)r * 64 + pos] = (_Float16)w_out[(size_t)k * 2048 + r];
        }
    } else {
        const int e0 = (b - 624) * 512 + threadIdx.x;
        const int e1 = e0 + 256;
        if (e0 < N_EDGES_C) atomicAdd(&deg[col[e0]], 1);
        if (e1 < N_EDGES_C) atomicAdd(&deg[col[e1]], 1);
    }
}

// ---------------------------------------------------------------------------
// Fused: blocks [0, MLP_BLOCKS) = per-node MLP (wave-private LDS, zero
// barriers); blocks [MLP_BLOCKS, MLP_BLOCKS+196) = scan1 block sums.
// Both depend only on prep_deg.
// ---------------------------------------------------------------------------
__launch_bounds__(256, 4)
__global__ void mlp_scan1_kernel(const float* __restrict__ xf,
                                 const float* __restrict__ b_in,
                                 const float* __restrict__ b_mid,
                                 const _Float16* __restrict__ wT,
                                 _Float16* __restrict__ hG,
                                 const int* __restrict__ deg,
                                 int* __restrict__ bsum)
{
    __shared__ _Float16 hball[4][16 * XSTR];   // 4 x 2304 B
    __shared__ int ssum[4];

    if (blockIdx.x >= MLP_BLOCKS) {
        // ---------------- scan1 part ----------------
        const int t = threadIdx.x;
        const int i = (blockIdx.x - MLP_BLOCKS) * 256 + t;
        int v = (i < N_NODES_C) ? deg[i] : 0;
        #pragma unroll
        for (int d = 1; d < 64; d <<= 1) v += __shfl_xor(v, d);
        if ((t & 63) == 0) ssum[t >> 6] = v;
        __syncthreads();
        if (t == 0) bsum[blockIdx.x - MLP_BLOCKS] = ssum[0] + ssum[1] + ssum[2] + ssum[3];
        return;
    }

    // ---------------- MLP part ----------------
    const int t    = threadIdx.x;
    const int w    = t >> 6;
    const int lane = t & 63;
    const int quad = lane >> 4;
    const int lrow = lane & 15;
    const int node0 = blockIdx.x * 64 + w * 16;
    _Float16* hb = hball[w];

    // stage x -> f16 (lane: node lrow, cols [quad*16, quad*16+16))
    {
        const int n = min(node0 + lrow, N_NODES_C - 1);
        const float4* src4 = (const float4*)(xf + (size_t)n * 64 + quad * 16);
        _Float16 tmp[16];
        #pragma unroll
        for (int i = 0; i < 4; ++i) {
            const float4 v = src4[i];
            tmp[i * 4 + 0] = (_Float16)v.x;
            tmp[i * 4 + 1] = (_Float16)v.y;
            tmp[i * 4 + 2] = (_Float16)v.z;
            tmp[i * 4 + 3] = (_Float16)v.w;
        }
        *(f16x8*)&hb[lrow * XSTR + quad * 16]     = *(f16x8*)&tmp[0];
        *(f16x8*)&hb[lrow * XSTR + quad * 16 + 8] = *(f16x8*)&tmp[8];
    }

    // 7 layers, wave-private
    const _Float16* wTl = wT;
    const float* bsrc = b_in;
    for (int l = 0; l < 7; ++l) {
        const f16x8 A0 = *(const f16x8*)&hb[lrow * XSTR + quad * 8];
        const f16x8 A1 = *(const f16x8*)&hb[lrow * XSTR + 32 + quad * 8];
        #pragma unroll
        for (int Nt = 0; Nt < 4; ++Nt) {
            const f16x8 B0 = *(const f16x8*)(wTl + (Nt * 16 + lrow) * 64 + quad * 8);
            const f16x8 B1 = *(const f16x8*)(wTl + (Nt * 16 + lrow) * 64 + 32 + quad * 8);
            const float bias = bsrc[Nt * 16 + lrow];
            f32x4 C = {0.f, 0.f, 0.f, 0.f};
            C = __builtin_amdgcn_mfma_f32_16x16x32_f16(A0, B0, C, 0, 0, 0);
            C = __builtin_amdgcn_mfma_f32_16x16x32_f16(A1, B1, C, 0, 0, 0);
            #pragma unroll
            for (int r = 0; r < 4; ++r) {
                const float v = fmaxf(C[r] + bias, 0.f);
                hb[(quad * 4 + r) * XSTR + Nt * 16 + lrow] = (_Float16)v;
            }
        }
        wTl += 4096;
        bsrc = b_mid + (size_t)l * 64;
    }

    // dump -> hG
    {
        const int n = node0 + lrow;
        if (n < N_NODES_C) {
            const f16x8 v0 = *(const f16x8*)&hb[lrow * XSTR + quad * 16];
            const f16x8 v1 = *(const f16x8*)&hb[lrow * XSTR + quad * 16 + 8];
            *(f16x8*)(hG + (size_t)n * 64 + quad * 16)     = v0;
            *(f16x8*)(hG + (size_t)n * 64 + quad * 16 + 8) = v1;
        }
    }
}

// ---------------------------------------------------------------------------
// scan2: block-offset scan (single block); scan3: per-node exclusive prefix
// (+ pos copy + dinv).
// ---------------------------------------------------------------------------
__global__ void scan2_kernel(const int* __restrict__ bsum, int* __restrict__ boff,
                             int* __restrict__ rowptr)
{
    __shared__ int sh[256];
    const int t = threadIdx.x;
    const int v = (t < 196) ? bsum[t] : 0;
    sh[t] = v;
    __syncthreads();
    for (int d = 1; d < 256; d <<= 1) {
        const int u = (t >= d) ? sh[t - d] : 0;
        __syncthreads();
        sh[t] += u;
        __syncthreads();
    }
    if (t < 196) boff[t] = sh[t] - v;     // exclusive
    if (t == 0) rowptr[N_NODES_C] = N_EDGES_C;
}

__global__ void scan3_kernel(const int* __restrict__ deg, const int* __restrict__ boff,
                             int* __restrict__ rowptr, int* __restrict__ pos,
                             float* __restrict__ dinv)
{
    const int t = threadIdx.x;
    const int i = blockIdx.x * 256 + t;
    const int lane = t & 63, w = t >> 6;
    const int v = (i < N_NODES_C) ? deg[i] : 0;
    int inc = v;
    #pragma unroll
    for (int d = 1; d < 64; d <<= 1) {
        const int u = __shfl_up(inc, d);
        if (lane >= d) inc += u;
    }
    __shared__ int ws[4];
    if (lane == 63) ws[w] = inc;
    __syncthreads();
    int wo = 0;
    #pragma unroll
    for (int k = 0; k < 4; ++k) if (k < w) wo += ws[k];
    const int excl = boff[blockIdx.x] + wo + inc - v;
    if (i < N_NODES_C) {
        rowptr[i] = excl;
        pos[i] = excl;
        dinv[i] = (v > 0) ? rsqrtf((float)v) : 0.f;
    }
}

// ---------------------------------------------------------------------------
// Fused: blocks [0, QC_BLOCKS) = qcalc (R10 body, grid flattened:
// by = blockIdx.x & 3, bx = blockIdx.x >> 2); blocks >= QC_BLOCKS = CSR fill
// (2 edges/thread). Pairing: qcalc is MFMA/LDS-heavy, fill is atomic-latency —
// co-residency hides fill behind qcalc.
// ---------------------------------------------------------------------------
__launch_bounds__(256, 3)
__global__ void qcalc_fill_kernel(const float* __restrict__ xf,
                                  const _Float16* __restrict__ hG,
                                  const _Float16* __restrict__ W3T,
                                  const float* __restrict__ b_out,
                                  const float* __restrict__ dinv,
                                  float* __restrict__ qs,
                                  const int* __restrict__ row,
                                  const int* __restrict__ col,
                                  int* __restrict__ pos,
                                  int* __restrict__ src)
{
    __shared__ _Float16 ws3[2][4096];   // 2 x 8 KB

    if (blockIdx.x >= QC_BLOCKS) {
        // ---------------- fill part ----------------
        const int e0 = (blockIdx.x - QC_BLOCKS) * 512 + threadIdx.x;
        const int e1 = e0 + 256;
        if (e0 < N_EDGES_C) {
            const int slot = atomicAdd(&pos[col[e0]], 1);
            src[slot] = row[e0];
        }
        if (e1 < N_EDGES_C) {
            const int slot = atomicAdd(&pos[col[e1]], 1);
            src[slot] = row[e1];
        }
        return;
    }

    // ---------------- qcalc part ----------------
    const int t    = threadIdx.x;
    const int w    = t >> 6;
    const int lane = t & 63;
    const int quad = lane >> 4;
    const int lrow = lane & 15;

    const int by   = blockIdx.x & 3;
    const int bx   = blockIdx.x >> 2;
    const int y0   = by * 8;
    const int yend = y0 + 8;

    const int base = bx * 128 + w * 32;
    const int ra = base + lrow;
    const int rb = base + 16 + lrow;
    const int na = min(ra, N_NODES_C - 1);
    const int nb = min(rb, N_NODES_C - 1);

    // hoisted B-frags (h, f16) and x C-pattern frags (f32)
    f16x8 Bha[2], Bhb[2];
    #pragma unroll
    for (int ks = 0; ks < 2; ++ks) {
        Bha[ks] = *(const f16x8*)(hG + (size_t)na * 64 + ks * 32 + quad * 8);
        Bhb[ks] = *(const f16x8*)(hG + (size_t)nb * 64 + ks * 32 + quad * 8);
    }
    float4 xca[4], xcb[4];
    #pragma unroll
    for (int xt = 0; xt < 4; ++xt) {
        xca[xt] = *(const float4*)(xf + (size_t)na * 64 + xt * 16 + quad * 4);
        xcb[xt] = *(const float4*)(xf + (size_t)nb * 64 + xt * 16 + quad * 4);
    }
    const float dva = dinv[na];
    const float dvb = dinv[nb];

    // prefetch slice y0 (dense copy preserves the global-side swizzle)
    {
        const f16x8 v0 = *(const f16x8*)(W3T + (size_t)y0 * 4096 + t * 8);
        const f16x8 v1 = *(const f16x8*)(W3T + (size_t)y0 * 4096 + (t + 256) * 8);
        *(f16x8*)(&ws3[0][t * 8]) = v0;
        *(f16x8*)(&ws3[0][(t + 256) * 8]) = v1;
    }

    const int swz = lrow & 7;
    const int cp0 = ((quad)     ^ swz) * 8;   // ks=0 chunk offset (f16)
    const int cp1 = ((4 + quad) ^ swz) * 8;   // ks=1 chunk offset

    __syncthreads();

    for (int y = y0; y < yend; ++y) {
        // issue next slice's global loads early (lands during compute)
        f16x8 nv0, nv1;
        if (y + 1 < yend) {
            nv0 = *(const f16x8*)(W3T + (size_t)(y + 1) * 4096 + t * 8);
            nv1 = *(const f16x8*)(W3T + (size_t)(y + 1) * 4096 + (t + 256) * 8);
        }

        const _Float16* cur = ws3[y & 1];
        float qa = 0.f, qb = 0.f;
        #pragma unroll
        for (int xt = 0; xt < 4; ++xt) {
            const _Float16* rp = cur + (xt * 16 + lrow) * 64;
            const f16x8 A0 = *(const f16x8*)(rp + cp0);
            const f16x8 A1 = *(const f16x8*)(rp + cp1);
            f32x4 Ca = {0.f, 0.f, 0.f, 0.f};
            Ca = __builtin_amdgcn_mfma_f32_16x16x32_f16(A0, Bha[0], Ca, 0, 0, 0);
            Ca = __builtin_amdgcn_mfma_f32_16x16x32_f16(A1, Bha[1], Ca, 0, 0, 0);
            f32x4 Cb = {0.f, 0.f, 0.f, 0.f};
            Cb = __builtin_amdgcn_mfma_f32_16x16x32_f16(A0, Bhb[0], Cb, 0, 0, 0);
            Cb = __builtin_amdgcn_mfma_f32_16x16x32_f16(A1, Bhb[1], Cb, 0, 0, 0);

            const float4 bf = *(const float4*)(b_out + y * 64 + xt * 16 + quad * 4);
            qa += (Ca[0] + bf.x) * xca[xt].x + (Ca[1] + bf.y) * xca[xt].y
                + (Ca[2] + bf.z) * xca[xt].z + (Ca[3] + bf.w) * xca[xt].w;
            qb += (Cb[0] + bf.x) * xcb[xt].x + (Cb[1] + bf.y) * xcb[xt].y
                + (Cb[2] + bf.z) * xcb[xt].z + (Cb[3] + bf.w) * xcb[xt].w;
        }
        qa += __shfl_xor(qa, 16);
        qa += __shfl_xor(qa, 32);
        qb += __shfl_xor(qb, 16);
        qb += __shfl_xor(qb, 32);

        if (quad == (y >> 3)) {               // quad q stores y in [8q, 8q+8)
            if (ra < N_NODES_C) qs[(size_t)ra * 32 + y] = qa * dva;
            if (rb < N_NODES_C) qs[(size_t)rb * 32 + y] = qb * dvb;
        }

        if (y + 1 < yend) {
            _Float16* nxt = ws3[(y + 1) & 1];
            *(f16x8*)(&nxt[t * 8]) = nv0;
            *(f16x8*)(&nxt[(t + 256) * 8]) = nv1;
        }
        __syncthreads();
    }
}

// ---------------------------------------------------------------------------
// Gather: out[n,y] = dinv[n] * sum_{s in CSR row n} qs[src[s], y]
// ---------------------------------------------------------------------------
__global__ void gather_kernel(const int* __restrict__ rowptr, const int* __restrict__ src,
                              const float* __restrict__ qs, const float* __restrict__ dinv,
                              float* __restrict__ out)
{
    const int t = threadIdx.x;
    const int node = blockIdx.x * 8 + (t >> 5);
    const int y = t & 31;
    const int s0 = rowptr[node];
    const int s1 = rowptr[node + 1];
    float acc = 0.f;
    int s = s0;
    for (; s + 4 <= s1; s += 4) {
        const int r0 = src[s], r1 = src[s + 1], r2 = src[s + 2], r3 = src[s + 3];
        acc += qs[(size_t)r0 * 32 + y];
        acc += qs[(size_t)r1 * 32 + y];
        acc += qs[(size_t)r2 * 32 + y];
        acc += qs[(size_t)r3 * 32 + y];
    }
    for (; s < s1; ++s) acc += qs[(size_t)src[s] * 32 + y];
    out[(size_t)node * 32 + y] = acc * dinv[node];
}

// ---------------------------------------------------------------------------
extern "C" void kernel_launch(void* const* d_in, const int* in_sizes, int n_in,
                              void* d_out, int out_size, void* d_ws, size_t ws_size,
                              hipStream_t stream)
{
    const float* xf    = (const float*)d_in[0];
    const int*   eidx  = (const int*)d_in[1];
    const float* w_in  = (const float*)d_in[2];
    const float* b_in  = (const float*)d_in[3];
    const float* w_mid = (const float*)d_in[4];
    const float* b_mid = (const float*)d_in[5];
    const float* w_out = (const float*)d_in[6];
    const float* b_out = (const float*)d_in[7];
    float* out = (float*)d_out;

    const int* row = eidx;
    const int* col = eidx + N_EDGES_C;

    // workspace layout (bytes)
    char* ws = (char*)d_ws;
    float*    qs     = (float*)(ws + 0);            //  6,400,000
    int*      deg    = (int*)(ws + 6400000);        //    200,000
    float*    dinv   = (float*)(ws + 6600000);      //    200,000
    _Float16* wT     = (_Float16*)(ws + 6800000);   //     57,344
    _Float16* W3T    = (_Float16*)(ws + 6857344);   //    262,144
    _Float16* hG     = (_Float16*)(ws + 7119488);   //  6,400,000
    int*      rowptr = (int*)(ws + 13519488);       //    200,004
    int*      pos    = (int*)(ws + 13719492);       //    200,000
    int*      srcb   = (int*)(ws + 13919492);       //  3,200,000
    int*      bsum   = (int*)(ws + 17119492);       //        784
    int*      boff   = (int*)(ws + 17120276);       //        784

    hipMemsetAsync(deg, 0, N_NODES_C * sizeof(int), stream);

    prep_deg_kernel<<<dim3(624 + DEG_BLOCKS), dim3(256), 0, stream>>>(
        w_in, w_mid, w_out, col, wT, W3T, deg);

    mlp_scan1_kernel<<<dim3(MLP_BLOCKS + 196), dim3(256), 0, stream>>>(
        xf, b_in, b_mid, wT, hG, deg, bsum);

    scan2_kernel<<<dim3(1), dim3(256), 0, stream>>>(bsum, boff, rowptr);
    scan3_kernel<<<dim3(196), dim3(256), 0, stream>>>(deg, boff, rowptr, pos, dinv);

    qcalc_fill_kernel<<<dim3(QC_BLOCKS + DEG_BLOCKS), dim3(256), 0, stream>>>(
        xf, hG, W3T, b_out, dinv, qs, row, col, pos, srcb);

    gather_kernel<<<dim3(N_NODES_C / 8), dim3(256), 0, stream>>>(rowptr, srcb, qs, dinv, out);
}

// Round 12
// 218.634 us; speedup vs baseline: 1.1794x; 1.1794x over previous
//
#include <hip/hip_runtime.h>
#include <cstddef>

#define N_NODES_C 50000
#define N_EDGES_C 800000

typedef _Float16 f16x8 __attribute__((ext_vector_type(8)));
typedef float    f32x4 __attribute__((ext_vector_type(4)));

constexpr int XSTR = 72;          // f16 stride for per-wave h buffer
constexpr int MQ_BLOCKS  = 391;   // ceil(50000/128) mlp+qcalc blocks
constexpr int FILL_BLOCKS = 1563; // ceil(800000/512), 2 edges/thread
constexpr int DEG_BLOCKS  = 1563;

// ---------------------------------------------------------------------------
// prep (wT, W3T) + deg fused (deg: 2 edges/thread).
//  wT[l][j][k] = W_l[k][j] (f16)                      idx [0, 28672)
//  W3T[r=y*64+x][64 k] (f16), 16B chunks XOR-swizzled: chunk c of row r
//  stored at chunk c^(r&7). Value = w_out[k*2048 + r].   idx [28672, 159744)
// ---------------------------------------------------------------------------
__global__ void prep_deg_kernel(const float* __restrict__ w_in,
                                const float* __restrict__ w_mid,
                                const float* __restrict__ w_out,
                                const int* __restrict__ col,
                                _Float16* __restrict__ wT,
                                _Float16* __restrict__ W3T,
                                int* __restrict__ deg)
{
    const int b = blockIdx.x;
    if (b < 624) {
        const int idx = b * 256 + threadIdx.x;
        if (idx < 7 * 4096) {
            const int l = idx >> 12, rem = idx & 4095;
            const int j = rem >> 6, k = rem & 63;
            const float v = (l == 0) ? w_in[k * 64 + j]
                                     : w_mid[(size_t)(l - 1) * 4096 + k * 64 + j];
            wT[(size_t)l * 4096 + j * 64 + k] = (_Float16)v;
        } else {
            const int i2 = idx - 7 * 4096;   // < 131072
            const int r = i2 >> 6, k = i2 & 63;
            const int c = k >> 3;
            const int pos = ((c ^ (r & 7)) << 3) | (k & 7);
            W3T[(size_t)r * 64 + pos] = (_Float16)w_out[(size_t)k * 2048 + r];
        }
    } else {
        const int e0 = (b - 624) * 512 + threadIdx.x;
        const int e1 = e0 + 256;
        if (e0 < N_EDGES_C) atomicAdd(&deg[col[e0]], 1);
        if (e1 < N_EDGES_C) atomicAdd(&deg[col[e1]], 1);
    }
}

// ---------------------------------------------------------------------------
// 3-phase parallel scan (R10 verbatim); scan3 also emits dinv.
// ---------------------------------------------------------------------------
__global__ void scan1_kernel(const int* __restrict__ deg, int* __restrict__ bsum)
{
    const int t = threadIdx.x;
    const int i = blockIdx.x * 256 + t;
    int v = (i < N_NODES_C) ? deg[i] : 0;
    #pragma unroll
    for (int d = 1; d < 64; d <<= 1) v += __shfl_xor(v, d);
    __shared__ int s[4];
    if ((t & 63) == 0) s[t >> 6] = v;
    __syncthreads();
    if (t == 0) bsum[blockIdx.x] = s[0] + s[1] + s[2] + s[3];
}

__global__ void scan2_kernel(const int* __restrict__ bsum, int* __restrict__ boff,
                             int* __restrict__ rowptr)
{
    __shared__ int sh[256];
    const int t = threadIdx.x;
    const int v = (t < 196) ? bsum[t] : 0;
    sh[t] = v;
    __syncthreads();
    for (int d = 1; d < 256; d <<= 1) {
        const int u = (t >= d) ? sh[t - d] : 0;
        __syncthreads();
        sh[t] += u;
        __syncthreads();
    }
    if (t < 196) boff[t] = sh[t] - v;     // exclusive
    if (t == 0) rowptr[N_NODES_C] = N_EDGES_C;
}

__global__ void scan3_kernel(const int* __restrict__ deg, const int* __restrict__ boff,
                             int* __restrict__ rowptr, int* __restrict__ pos,
                             float* __restrict__ dinv)
{
    const int t = threadIdx.x;
    const int i = blockIdx.x * 256 + t;
    const int lane = t & 63, w = t >> 6;
    const int v = (i < N_NODES_C) ? deg[i] : 0;
    int inc = v;
    #pragma unroll
    for (int d = 1; d < 64; d <<= 1) {
        const int u = __shfl_up(inc, d);
        if (lane >= d) inc += u;
    }
    __shared__ int ws[4];
    if (lane == 63) ws[w] = inc;
    __syncthreads();
    int wo = 0;
    #pragma unroll
    for (int k = 0; k < 4; ++k) if (k < w) wo += ws[k];
    const int excl = boff[blockIdx.x] + wo + inc - v;
    if (i < N_NODES_C) {
        rowptr[i] = excl;
        pos[i] = excl;
        dinv[i] = (v > 0) ? rsqrtf((float)v) : 0.f;
    }
}

// ---------------------------------------------------------------------------
// MEGA kernel.
//  Blocks [0, MQ_BLOCKS): 128 nodes each, 4 waves x 32 nodes.
//    Phase 1: per-wave MLP (wave-private hb LDS, zero barriers), h stays in LDS.
//    Phase 2: qcalc over ALL 32 y (R4/R10 double-buffered W3T loop); h B-frags
//    read from the wave's own hb — no hG global round-trip.
//  Blocks >= MQ_BLOCKS: CSR fill (2 edges/thread) — co-resident from t=0
//    because only 391 compute blocks exist (~1.5/CU).
// ---------------------------------------------------------------------------
__launch_bounds__(256, 3)
__global__ void mega_kernel(const float* __restrict__ xf,
                            const float* __restrict__ b_in,
                            const float* __restrict__ b_mid,
                            const _Float16* __restrict__ wT,
                            const _Float16* __restrict__ W3T,
                            const float* __restrict__ b_out,
                            const float* __restrict__ dinv,
                            float* __restrict__ qs,
                            const int* __restrict__ row,
                            const int* __restrict__ col,
                            int* __restrict__ pos,
                            int* __restrict__ src)
{
    __shared__ _Float16 hball[4][32 * XSTR];   // 4 x 4608 B = 18432 B
    __shared__ _Float16 ws3[2][4096];          // 16384 B

    if (blockIdx.x >= MQ_BLOCKS) {
        // ---------------- fill part ----------------
        const int e0 = (blockIdx.x - MQ_BLOCKS) * 512 + threadIdx.x;
        const int e1 = e0 + 256;
        if (e0 < N_EDGES_C) {
            const int slot = atomicAdd(&pos[col[e0]], 1);
            src[slot] = row[e0];
        }
        if (e1 < N_EDGES_C) {
            const int slot = atomicAdd(&pos[col[e1]], 1);
            src[slot] = row[e1];
        }
        return;
    }

    const int t    = threadIdx.x;
    const int w    = t >> 6;
    const int lane = t & 63;
    const int quad = lane >> 4;
    const int lrow = lane & 15;
    const int node0 = blockIdx.x * 128 + w * 32;
    _Float16* hb = hball[w];

    // ---- phase 1a: stage x -> f16 hb (2 groups of 16 nodes) ----
    #pragma unroll
    for (int g = 0; g < 2; ++g) {
        const int nl = g * 16 + lrow;
        const int n = min(node0 + nl, N_NODES_C - 1);
        const float4* src4 = (const float4*)(xf + (size_t)n * 64 + quad * 16);
        _Float16 tmp[16];
        #pragma unroll
        for (int i = 0; i < 4; ++i) {
            const float4 v = src4[i];
            tmp[i * 4 + 0] = (_Float16)v.x;
            tmp[i * 4 + 1] = (_Float16)v.y;
            tmp[i * 4 + 2] = (_Float16)v.z;
            tmp[i * 4 + 3] = (_Float16)v.w;
        }
        *(f16x8*)&hb[nl * XSTR + quad * 16]     = *(f16x8*)&tmp[0];
        *(f16x8*)&hb[nl * XSTR + quad * 16 + 8] = *(f16x8*)&tmp[8];
    }

    // ---- phase 1b: 7 layers, wave-private, 32 nodes/wave ----
    {
        const _Float16* wTl = wT;
        const float* bsrc = b_in;
        for (int l = 0; l < 7; ++l) {
            const f16x8 A0a = *(const f16x8*)&hb[lrow * XSTR + quad * 8];
            const f16x8 A1a = *(const f16x8*)&hb[lrow * XSTR + 32 + quad * 8];
            const f16x8 A0b = *(const f16x8*)&hb[(16 + lrow) * XSTR + quad * 8];
            const f16x8 A1b = *(const f16x8*)&hb[(16 + lrow) * XSTR + 32 + quad * 8];
            #pragma unroll
            for (int Nt = 0; Nt < 4; ++Nt) {
                const f16x8 B0 = *(const f16x8*)(wTl + (Nt * 16 + lrow) * 64 + quad * 8);
                const f16x8 B1 = *(const f16x8*)(wTl + (Nt * 16 + lrow) * 64 + 32 + quad * 8);
                const float bias = bsrc[Nt * 16 + lrow];
                f32x4 Ca = {0.f, 0.f, 0.f, 0.f};
                Ca = __builtin_amdgcn_mfma_f32_16x16x32_f16(A0a, B0, Ca, 0, 0, 0);
                Ca = __builtin_amdgcn_mfma_f32_16x16x32_f16(A1a, B1, Ca, 0, 0, 0);
                f32x4 Cb = {0.f, 0.f, 0.f, 0.f};
                Cb = __builtin_amdgcn_mfma_f32_16x16x32_f16(A0b, B0, Cb, 0, 0, 0);
                Cb = __builtin_amdgcn_mfma_f32_16x16x32_f16(A1b, B1, Cb, 0, 0, 0);
                #pragma unroll
                for (int r = 0; r < 4; ++r) {
                    const float va = fmaxf(Ca[r] + bias, 0.f);
                    const float vb = fmaxf(Cb[r] + bias, 0.f);
                    hb[(quad * 4 + r) * XSTR + Nt * 16 + lrow]        = (_Float16)va;
                    hb[(16 + quad * 4 + r) * XSTR + Nt * 16 + lrow]   = (_Float16)vb;
                }
            }
            wTl += 4096;
            bsrc = b_mid + (size_t)l * 64;
        }
    }

    // ---- phase 2 setup: B-frags (h) from wave-private LDS, x/dinv from global
    const int ra = node0 + lrow;
    const int rb = node0 + 16 + lrow;
    const int na = min(ra, N_NODES_C - 1);
    const int nb = min(rb, N_NODES_C - 1);

    f16x8 Bha[2], Bhb[2];
    #pragma unroll
    for (int ks = 0; ks < 2; ++ks) {
        Bha[ks] = *(const f16x8*)&hb[lrow * XSTR + ks * 32 + quad * 8];
        Bhb[ks] = *(const f16x8*)&hb[(16 + lrow) * XSTR + ks * 32 + quad * 8];
    }
    float4 xca[4], xcb[4];
    #pragma unroll
    for (int xt = 0; xt < 4; ++xt) {
        xca[xt] = *(const float4*)(xf + (size_t)na * 64 + xt * 16 + quad * 4);
        xcb[xt] = *(const float4*)(xf + (size_t)nb * 64 + xt * 16 + quad * 4);
    }
    const float dva = dinv[na];
    const float dvb = dinv[nb];

    // prefetch slice y=0 (dense copy preserves the global-side swizzle)
    {
        const f16x8 v0 = *(const f16x8*)(W3T + (size_t)t * 8);
        const f16x8 v1 = *(const f16x8*)(W3T + (size_t)(t + 256) * 8);
        *(f16x8*)(&ws3[0][t * 8]) = v0;
        *(f16x8*)(&ws3[0][(t + 256) * 8]) = v1;
    }

    const int swz = lrow & 7;
    const int cp0 = ((quad)     ^ swz) * 8;   // ks=0 chunk offset (f16)
    const int cp1 = ((4 + quad) ^ swz) * 8;   // ks=1 chunk offset

    __syncthreads();

    // ---- phase 2: qcalc over all 32 y (double-buffered W3T slices) ----
    for (int y = 0; y < 32; ++y) {
        f16x8 nv0, nv1;
        if (y + 1 < 32) {
            nv0 = *(const f16x8*)(W3T + (size_t)(y + 1) * 4096 + t * 8);
            nv1 = *(const f16x8*)(W3T + (size_t)(y + 1) * 4096 + (t + 256) * 8);
        }

        const _Float16* cur = ws3[y & 1];
        float qa = 0.f, qb = 0.f;
        #pragma unroll
        for (int xt = 0; xt < 4; ++xt) {
            const _Float16* rp = cur + (xt * 16 + lrow) * 64;
            const f16x8 A0 = *(const f16x8*)(rp + cp0);
            const f16x8 A1 = *(const f16x8*)(rp + cp1);
            f32x4 Ca = {0.f, 0.f, 0.f, 0.f};
            Ca = __builtin_amdgcn_mfma_f32_16x16x32_f16(A0, Bha[0], Ca, 0, 0, 0);
            Ca = __builtin_amdgcn_mfma_f32_16x16x32_f16(A1, Bha[1], Ca, 0, 0, 0);
            f32x4 Cb = {0.f, 0.f, 0.f, 0.f};
            Cb = __builtin_amdgcn_mfma_f32_16x16x32_f16(A0, Bhb[0], Cb, 0, 0, 0);
            Cb = __builtin_amdgcn_mfma_f32_16x16x32_f16(A1, Bhb[1], Cb, 0, 0, 0);

            const float4 bf = *(const float4*)(b_out + y * 64 + xt * 16 + quad * 4);
            qa += (Ca[0] + bf.x) * xca[xt].x + (Ca[1] + bf.y) * xca[xt].y
                + (Ca[2] + bf.z) * xca[xt].z + (Ca[3] + bf.w) * xca[xt].w;
            qb += (Cb[0] + bf.x) * xcb[xt].x + (Cb[1] + bf.y) * xcb[xt].y
                + (Cb[2] + bf.z) * xcb[xt].z + (Cb[3] + bf.w) * xcb[xt].w;
        }
        qa += __shfl_xor(qa, 16);
        qa += __shfl_xor(qa, 32);
        qb += __shfl_xor(qb, 16);
        qb += __shfl_xor(qb, 32);

        if (quad == (y >> 3)) {               // quad q stores y in [8q, 8q+8)
            if (ra < N_NODES_C) qs[(size_t)ra * 32 + y] = qa * dva;
            if (rb < N_NODES_C) qs[(size_t)rb * 32 + y] = qb * dvb;
        }

        if (y + 1 < 32) {
            _Float16* nxt = ws3[(y + 1) & 1];
            *(f16x8*)(&nxt[t * 8]) = nv0;
            *(f16x8*)(&nxt[(t + 256) * 8]) = nv1;
        }
        __syncthreads();
    }
}

// ---------------------------------------------------------------------------
// Gather: out[n,y] = dinv[n] * sum_{s in CSR row n} qs[src[s], y]
// ---------------------------------------------------------------------------
__global__ void gather_kernel(const int* __restrict__ rowptr, const int* __restrict__ src,
                              const float* __restrict__ qs, const float* __restrict__ dinv,
                              float* __restrict__ out)
{
    const int t = threadIdx.x;
    const int node = blockIdx.x * 8 + (t >> 5);
    const int y = t & 31;
    const int s0 = rowptr[node];
    const int s1 = rowptr[node + 1];
    float acc = 0.f;
    int s = s0;
    for (; s + 4 <= s1; s += 4) {
        const int r0 = src[s], r1 = src[s + 1], r2 = src[s + 2], r3 = src[s + 3];
        acc += qs[(size_t)r0 * 32 + y];
        acc += qs[(size_t)r1 * 32 + y];
        acc += qs[(size_t)r2 * 32 + y];
        acc += qs[(size_t)r3 * 32 + y];
    }
    for (; s < s1; ++s) acc += qs[(size_t)src[s] * 32 + y];
    out[(size_t)node * 32 + y] = acc * dinv[node];
}

// ---------------------------------------------------------------------------
extern "C" void kernel_launch(void* const* d_in, const int* in_sizes, int n_in,
                              void* d_out, int out_size, void* d_ws, size_t ws_size,
                              hipStream_t stream)
{
    const float* xf    = (const float*)d_in[0];
    const int*   eidx  = (const int*)d_in[1];
    const float* w_in  = (const float*)d_in[2];
    const float* b_in  = (const float*)d_in[3];
    const float* w_mid = (const float*)d_in[4];
    const float* b_mid = (const float*)d_in[5];
    const float* w_out = (const float*)d_in[6];
    const float* b_out = (const float*)d_in[7];
    float* out = (float*)d_out;

    const int* row = eidx;
    const int* col = eidx + N_EDGES_C;

    // workspace layout (bytes)
    char* ws = (char*)d_ws;
    float*    qs     = (float*)(ws + 0);            //  6,400,000
    int*      deg    = (int*)(ws + 6400000);        //    200,000
    float*    dinv   = (float*)(ws + 6600000);      //    200,000
    _Float16* wT     = (_Float16*)(ws + 6800000);   //     57,344
    _Float16* W3T    = (_Float16*)(ws + 6857344);   //    262,144
    int*      rowptr = (int*)(ws + 7119488);        //    200,004
    int*      pos    = (int*)(ws + 7319492);        //    200,000
    int*      srcb   = (int*)(ws + 7519492);        //  3,200,000
    int*      bsum   = (int*)(ws + 10719492);       //        784
    int*      boff   = (int*)(ws + 10720276);       //        784

    hipMemsetAsync(deg, 0, N_NODES_C * sizeof(int), stream);

    prep_deg_kernel<<<dim3(624 + DEG_BLOCKS), dim3(256), 0, stream>>>(
        w_in, w_mid, w_out, col, wT, W3T, deg);

    scan1_kernel<<<dim3(196), dim3(256), 0, stream>>>(deg, bsum);
    scan2_kernel<<<dim3(1), dim3(256), 0, stream>>>(bsum, boff, rowptr);
    scan3_kernel<<<dim3(196), dim3(256), 0, stream>>>(deg, boff, rowptr, pos, dinv);

    mega_kernel<<<dim3(MQ_BLOCKS + FILL_BLOCKS), dim3(256), 0, stream>>>(
        xf, b_in, b_mid, wT, W3T, b_out, dinv, qs, row, col, pos, srcb);

    gather_kernel<<<dim3(N_NODES_C / 8), dim3(256), 0, stream>>>(rowptr, srcb, qs, dinv, out);
}